// Round 2
// baseline (36460.529 us; speedup 1.0000x reference)
//
#include <hip/hip_runtime.h>

// ============================================================================
// Perceiver Resampler. Interface dtype auto-detected (fp32 vs bf16) at
// runtime from the bit pattern of x; internal compute bf16 MFMA + fp32
// accum/residual. B*T = 32 groups, 1024 media tokens, 64 latents, D=1024.
// ============================================================================

typedef unsigned short u16;  // raw bf16 bits
typedef __attribute__((ext_vector_type(8))) short short8;
typedef __attribute__((ext_vector_type(4))) float f32x4;

__device__ __forceinline__ float bf2f(u16 u) {
  return __uint_as_float(((unsigned)u) << 16);
}
__device__ __forceinline__ u16 f2bf(float f) {
  unsigned u = __float_as_uint(f);
  unsigned r = (u + 0x7FFFu + ((u >> 16) & 1u)) >> 16;  // RNE
  return (u16)r;
}

// ---------------------------------------------------------------------------
// Dtype detector: bf16 N(0,1) data has exponent field in [115,133] at even
// u16 indices; fp32 data's even u16s are mantissa bits (uniform exponent).
// flag=1 -> interface arrays are bf16; flag=0 -> fp32.
// ---------------------------------------------------------------------------
__global__ void detect_kernel(const u16* __restrict__ x, int* __restrict__ flag) {
  int lane = threadIdx.x;  // 64 threads
  u16 u = x[2 * lane];
  int e = (u >> 7) & 0xFF;
  unsigned long long b = __ballot(e >= 115 && e <= 133);
  if (lane == 0) flag[0] = (__popcll(b) >= 40) ? 1 : 0;
}

// ---------------------------------------------------------------------------
// GEMM: C[M,N] = A[M,K] @ B[K,N]; A bf16 row-major; B bf16 or fp32 (flag).
// EPI 0: store bf16. EPI 1: exact GELU -> bf16. EPI 2: fp32 store + residual R.
// 128x128 block tile, 4 waves 2x2, each wave 64x64 via 4x4 mfma 16x16x32.
// B transposed on the GLOBAL-read side (K-strided coalesced loads, one
// ds_write_b128 per 8 elems) -- the old LDS-side u16 scatter was a 16-way
// bank conflict (2.7e8 conflict cycles/dispatch). Pad 74 u16 = 37 words
// (odd) so consecutive-row vector ops spread across all 32 banks.
// XCD-aware swizzle: contiguous tile chunks per XCD share B panels in L2.
// ---------------------------------------------------------------------------
template <int EPI>
__global__ __launch_bounds__(256, 4)
void gemm_kernel(const u16* __restrict__ A, const void* __restrict__ Bv,
                 long Boff, void* __restrict__ Cp, const float* __restrict__ R,
                 int M, int N, int K, const int* __restrict__ flag) {
  __shared__ u16 As[128][74];
  __shared__ u16 Bs[128][74];  // Bs[n][k] (transposed)

  const int isb = *flag;
  const u16*   B16 = (const u16*)Bv + Boff;
  const float* B32 = (const float*)Bv + Boff;

  const int tid  = threadIdx.x;
  const int lane = tid & 63;
  const int wave = tid >> 6;
  const int wm = (wave >> 1) * 64;
  const int wn = (wave & 1) * 64;
  const int r  = lane & 15;
  const int qd = lane >> 4;

  // XCD-aware bijective swizzle (all launch grids have nwg % 8 == 0):
  // XCD c gets a contiguous chunk of logical tiles, x-fastest -> shared B panel.
  int bx = blockIdx.x, by = blockIdx.y;
  {
    const int nwg = gridDim.x * gridDim.y;
    if ((nwg & 7) == 0) {
      int flat = by * gridDim.x + bx;
      int swz = (flat & 7) * (nwg >> 3) + (flat >> 3);
      bx = swz % gridDim.x;
      by = swz / gridDim.x;
    }
  }
  const long bm = (long)bx * 128;
  const long bn = (long)by * 128;

  f32x4 acc[4][4];
#pragma unroll
  for (int i = 0; i < 4; ++i)
#pragma unroll
    for (int j = 0; j < 4; ++j) acc[i][j] = (f32x4){0.f, 0.f, 0.f, 0.f};

  const int ra = tid >> 3, ca = (tid & 7) * 8;   // A stage
  const int nb = tid & 127;                      // B stage: column within tile
  const int kh2 = tid >> 7;                      // 0..1: which 8-k chunk
  const u16* Aptr = A + (bm + ra) * (long)K + ca;

  for (int k0 = 0; k0 < K; k0 += 64) {
#pragma unroll
    for (int it = 0; it < 4; ++it) {  // A tile 128x64
      int4 av = *(const int4*)(Aptr + (long)(it * 32) * K + k0);
      *(int4*)(&As[ra + it * 32][ca]) = av;
    }
    if (isb) {
#pragma unroll
      for (int it = 0; it < 4; ++it) {  // B tile 64x128 (bf16): K-strided
        const int kb = it * 16 + kh2 * 8;
        const u16* bp = B16 + (long)(k0 + kb) * N + bn + nb;
        union { u16 u[8]; int4 v; } t;
#pragma unroll
        for (int j = 0; j < 8; ++j) t.u[j] = bp[(long)j * N];
        *(int4*)&Bs[nb][kb] = t.v;
      }
    } else {
#pragma unroll
      for (int it = 0; it < 4; ++it) {  // B tile 64x128 (fp32): K-strided + cvt
        const int kb = it * 16 + kh2 * 8;
        const float* bp = B32 + (long)(k0 + kb) * N + bn + nb;
        union { u16 u[8]; int4 v; } t;
#pragma unroll
        for (int j = 0; j < 8; ++j) t.u[j] = f2bf(bp[(long)j * N]);
        *(int4*)&Bs[nb][kb] = t.v;
      }
    }
    __syncthreads();

#pragma unroll
    for (int kh = 0; kh < 2; ++kh) {
      short8 af[4], bfv[4];
#pragma unroll
      for (int mt = 0; mt < 4; ++mt)
        af[mt] = *(const short8*)(&As[wm + mt * 16 + r][kh * 32 + qd * 8]);
#pragma unroll
      for (int nt = 0; nt < 4; ++nt)
        bfv[nt] = *(const short8*)(&Bs[wn + nt * 16 + r][kh * 32 + qd * 8]);
#pragma unroll
      for (int mt = 0; mt < 4; ++mt)
#pragma unroll
        for (int nt = 0; nt < 4; ++nt)
          acc[mt][nt] = __builtin_amdgcn_mfma_f32_16x16x32_bf16(
              af[mt], bfv[nt], acc[mt][nt], 0, 0, 0);
    }
    __syncthreads();
  }

  // C/D layout: col = lane&15, row = quad*4 + reg  [m89-verified]
#pragma unroll
  for (int mt = 0; mt < 4; ++mt) {
#pragma unroll
    for (int i = 0; i < 4; ++i) {
      long row = bm + wm + mt * 16 + qd * 4 + i;
#pragma unroll
      for (int nt = 0; nt < 4; ++nt) {
        long col = bn + wn + nt * 16 + r;
        long idx = row * N + col;
        float v = acc[mt][nt][i];
        if (EPI == 0) {
          ((u16*)Cp)[idx] = f2bf(v);
        } else if (EPI == 1) {
          float gl = 0.5f * v * (1.0f + erff(v * 0.70710678118654752f));
          ((u16*)Cp)[idx] = f2bf(gl);
        } else {
          ((float*)Cp)[idx] = v + R[idx];
        }
      }
    }
  }
}

// ---------------------------------------------------------------------------
// LayerNorm over last dim (1024). One block (256 thr) per row.
// INMODE 0: input dtype follows flag (d_in array). INMODE 1: input fp32 (lat).
// OUTMODE 0: bf16 out (internal). OUTMODE 1: out dtype follows flag (d_out).
// gamma/beta are d_in arrays -> dtype follows flag.
// ---------------------------------------------------------------------------
template <int INMODE, int OUTMODE>
__global__ __launch_bounds__(256)
void ln_kernel(const void* __restrict__ inp, long ioff,
               const void* __restrict__ gam, const void* __restrict__ bet,
               long goff, void* __restrict__ outp, const int* __restrict__ flag) {
  const int isb = *flag;
  const long row = blockIdx.x;
  const int tid = threadIdx.x;
  float x0, x1, x2, x3;
  const bool in_f32 = (INMODE == 1) || (!isb);
  if (in_f32) {
    float4 v = *((const float4*)((const float*)inp + ioff + row * 1024) + tid);
    x0 = v.x; x1 = v.y; x2 = v.z; x3 = v.w;
  } else {
    ushort4 u = *((const ushort4*)((const u16*)inp + ioff + row * 1024) + tid);
    x0 = bf2f(u.x); x1 = bf2f(u.y); x2 = bf2f(u.z); x3 = bf2f(u.w);
  }
  float s1 = x0 + x1 + x2 + x3;
  float s2 = x0 * x0 + x1 * x1 + x2 * x2 + x3 * x3;
#pragma unroll
  for (int off = 32; off >= 1; off >>= 1) {
    s1 += __shfl_xor(s1, off);
    s2 += __shfl_xor(s2, off);
  }
  __shared__ float r1[4], r2[4];
  if ((tid & 63) == 0) { r1[tid >> 6] = s1; r2[tid >> 6] = s2; }
  __syncthreads();
  s1 = r1[0] + r1[1] + r1[2] + r1[3];
  s2 = r2[0] + r2[1] + r2[2] + r2[3];
  const float mean = s1 * (1.0f / 1024.0f);
  const float var  = s2 * (1.0f / 1024.0f) - mean * mean;
  const float rstd = rsqrtf(var + 1e-5f);
  float g0, g1, g2, g3, b0, b1, b2, b3;
  if (isb) {
    ushort4 ug = *((const ushort4*)((const u16*)gam + goff) + tid);
    ushort4 ub = *((const ushort4*)((const u16*)bet + goff) + tid);
    g0 = bf2f(ug.x); g1 = bf2f(ug.y); g2 = bf2f(ug.z); g3 = bf2f(ug.w);
    b0 = bf2f(ub.x); b1 = bf2f(ub.y); b2 = bf2f(ub.z); b3 = bf2f(ub.w);
  } else {
    float4 vg = *((const float4*)((const float*)gam + goff) + tid);
    float4 vb = *((const float4*)((const float*)bet + goff) + tid);
    g0 = vg.x; g1 = vg.y; g2 = vg.z; g3 = vg.w;
    b0 = vb.x; b1 = vb.y; b2 = vb.z; b3 = vb.w;
  }
  float o0 = (x0 - mean) * rstd * g0 + b0;
  float o1 = (x1 - mean) * rstd * g1 + b1;
  float o2 = (x2 - mean) * rstd * g2 + b2;
  float o3 = (x3 - mean) * rstd * g3 + b3;
  const bool out_f32 = (OUTMODE == 1) && (!isb);
  if (out_f32) {
    float4 o = {o0, o1, o2, o3};
    *((float4*)((float*)outp + row * 1024) + tid) = o;
  } else {
    ushort4 o;
    o.x = f2bf(o0); o.y = f2bf(o1); o.z = f2bf(o2); o.w = f2bf(o3);
    *((ushort4*)((u16*)outp + row * 1024) + tid) = o;
  }
}

// ---------------------------------------------------------------------------
// lat[g][n][d] = latents[n][d] (fp32), g=0..31
// ---------------------------------------------------------------------------
__global__ __launch_bounds__(256)
void init_lat_kernel(const void* __restrict__ latents, float* __restrict__ lat,
                     const int* __restrict__ flag) {
  const int isb = *flag;
  long i = (long)blockIdx.x * 256 + threadIdx.x;  // one thread per 4 elems
  long src = (4 * i) & 65535;
  float4 o;
  if (isb) {
    ushort4 u = *(const ushort4*)((const u16*)latents + src);
    o = (float4){bf2f(u.x), bf2f(u.y), bf2f(u.z), bf2f(u.w)};
  } else {
    o = *(const float4*)((const float*)latents + src);
  }
  *(float4*)(lat + 4 * i) = o;
}

// ---------------------------------------------------------------------------
// Attention (MFMA flash): one block per (local g, h). 64 queries, 1088 keys
// in 17 tiles of 64. 4 waves x 16 query rows each. bf16 MFMA 16x16x32 for
// QK^T and PV; online softmax in registers (16-lane shfl reduces); P staged
// through LDS (reusing the Q buffer; Q hoisted to registers); V staged
// transposed for the PV B-fragment.
// ---------------------------------------------------------------------------
__global__ __launch_bounds__(256, 2)
void attn_kernel(const u16* __restrict__ Q, const u16* __restrict__ KVM,
                 const u16* __restrict__ KVL, u16* __restrict__ O, int g0) {
  const int gl = blockIdx.x;
  const int g  = g0 + gl;
  const int h  = blockIdx.y;
  __shared__ u16 k_s[64][72];    // K tile, row-major [j][d]
  __shared__ u16 vt_s[64][72];   // V tile transposed [d][j]
  __shared__ u16 qp_s[64][72];   // Q tile, then reused as bf16 P tile [q][j]

  const int tid  = threadIdx.x;
  const int lane = tid & 63;
  const int wave = tid >> 6;
  const int r  = lane & 15;
  const int qd = lane >> 4;
  const int qr = wave * 16;      // this wave's query-row base

  {  // stage Q (bf16, unscaled; 0.125 scale folded into softmax)
    const int rr = tid >> 2, cc = (tid & 3) * 16;
    const u16* qp = Q + ((long)g * 64 + rr) * 1024 + h * 64 + cc;
    *(int4*)&qp_s[rr][cc]     = *(const int4*)qp;
    *(int4*)&qp_s[rr][cc + 8] = *(const int4*)(qp + 8);
  }
  __syncthreads();

  // Q A-fragments live in registers for all 17 tiles (qp_s becomes P below)
  short8 aq0 = *(const short8*)&qp_s[qr + r][qd * 8];
  short8 aq1 = *(const short8*)&qp_s[qr + r][32 + qd * 8];

  f32x4 acc_o[4];
  float m0[4], l0[4];
#pragma unroll
  for (int i = 0; i < 4; ++i) {
    m0[i] = -3.0e38f;
    l0[i] = 0.f;
    acc_o[i] = (f32x4){0.f, 0.f, 0.f, 0.f};
  }

  for (int t = 0; t < 17; ++t) {
    const u16* base = (t < 16)
        ? KVM + ((long)gl * 1024 + t * 64) * 2048 + h * 64
        : KVL + ((long)g * 64) * 2048 + h * 64;
    {  // K tile 64x64 row-major, vector copy
      const int rr = tid >> 2, cc = (tid & 3) * 16;
      const u16* kp = base + (long)rr * 2048 + cc;
      *(int4*)&k_s[rr][cc]     = *(const int4*)kp;
      *(int4*)&k_s[rr][cc + 8] = *(const int4*)(kp + 8);
    }
    {  // V tile transposed: vt_s[d][j] = V[j][d]; coalesced 2B/lane loads,
       // contiguous-j register accumulate -> 2x b128 LDS writes
      const int d = lane;
      const u16* vp = base + 1024 + (long)(wave * 16) * 2048 + d;
      union { u16 u[16]; int4 v[2]; } tmp;
#pragma unroll
      for (int u = 0; u < 16; ++u) tmp.u[u] = vp[(long)u * 2048];
      *(int4*)&vt_s[d][wave * 16]     = tmp.v[0];
      *(int4*)&vt_s[d][wave * 16 + 8] = tmp.v[1];
    }
    __syncthreads();

    // --- S = Q @ K^T (wave rows qr..qr+15, cols 0..63) ---
    f32x4 sac[4];
#pragma unroll
    for (int nt = 0; nt < 4; ++nt) sac[nt] = (f32x4){0.f, 0.f, 0.f, 0.f};
#pragma unroll
    for (int nt = 0; nt < 4; ++nt) {
      short8 b0 = *(const short8*)&k_s[nt * 16 + r][qd * 8];
      short8 b1 = *(const short8*)&k_s[nt * 16 + r][32 + qd * 8];
      sac[nt] = __builtin_amdgcn_mfma_f32_16x16x32_bf16(aq0, b0, sac[nt], 0, 0, 0);
      sac[nt] = __builtin_amdgcn_mfma_f32_16x16x32_bf16(aq1, b1, sac[nt], 0, 0, 0);
    }

    // --- online softmax; lane's rows are qr+qd*4+i, cols nt*16+r ---
    float pr[4][4];
#pragma unroll
    for (int nt = 0; nt < 4; ++nt)
#pragma unroll
      for (int i = 0; i < 4; ++i) pr[nt][i] = sac[nt][i] * 0.125f;

#pragma unroll
    for (int i = 0; i < 4; ++i) {
      float mt = fmaxf(fmaxf(pr[0][i], pr[1][i]), fmaxf(pr[2][i], pr[3][i]));
      mt = fmaxf(mt, __shfl_xor(mt, 1));
      mt = fmaxf(mt, __shfl_xor(mt, 2));
      mt = fmaxf(mt, __shfl_xor(mt, 4));
      mt = fmaxf(mt, __shfl_xor(mt, 8));
      float mn = fmaxf(m0[i], mt);
      float al = __expf(m0[i] - mn);
      m0[i] = mn;
      float ts = 0.f;
#pragma unroll
      for (int nt = 0; nt < 4; ++nt) {
        float p = __expf(pr[nt][i] - mn);
        pr[nt][i] = p;
        ts += p;
      }
      ts += __shfl_xor(ts, 1);
      ts += __shfl_xor(ts, 2);
      ts += __shfl_xor(ts, 4);
      ts += __shfl_xor(ts, 8);
      l0[i] = l0[i] * al + ts;
#pragma unroll
      for (int nt = 0; nt < 4; ++nt) acc_o[nt][i] *= al;
    }

    // P -> bf16 into qp_s (each wave writes only its own 16 rows)
#pragma unroll
    for (int nt = 0; nt < 4; ++nt)
#pragma unroll
      for (int i = 0; i < 4; ++i)
        qp_s[qr + qd * 4 + i][nt * 16 + r] = f2bf(pr[nt][i]);

    // --- O += P @ V ---
    short8 ap0 = *(const short8*)&qp_s[qr + r][qd * 8];
    short8 ap1 = *(const short8*)&qp_s[qr + r][32 + qd * 8];
#pragma unroll
    for (int nt = 0; nt < 4; ++nt) {
      short8 b0 = *(const short8*)&vt_s[nt * 16 + r][qd * 8];
      short8 b1 = *(const short8*)&vt_s[nt * 16 + r][32 + qd * 8];
      acc_o[nt] = __builtin_amdgcn_mfma_f32_16x16x32_bf16(ap0, b0, acc_o[nt], 0, 0, 0);
      acc_o[nt] = __builtin_amdgcn_mfma_f32_16x16x32_bf16(ap1, b1, acc_o[nt], 0, 0, 0);
    }
    __syncthreads();
  }

  // epilogue: O row = g*64 + qr + qd*4 + i, col = h*64 + nt*16 + r
#pragma unroll
  for (int i = 0; i < 4; ++i) {
    float inv = 1.0f / l0[i];
    long row = (long)g * 64 + qr + qd * 4 + i;
#pragma unroll
    for (int nt = 0; nt < 4; ++nt)
      O[row * 1024 + h * 64 + nt * 16 + r] = f2bf(acc_o[nt][i] * inv);
  }
}

// ---------------------------------------------------------------------------
extern "C" void kernel_launch(void* const* d_in, const int* in_sizes, int n_in,
                              void* d_out, int out_size, void* d_ws, size_t ws_size,
                              hipStream_t stream) {
  const void* x     = d_in[0];   // [32][1024][1024]
  const void* lats  = d_in[1];   // [64][1024]
  const void* nm_g  = d_in[2];
  const void* nm_b  = d_in[3];
  const void* nl_g  = d_in[4];
  const void* nl_b  = d_in[5];
  const void* wq    = d_in[6];   // [6][1024][1024]
  const void* wkv   = d_in[7];   // [6][1024][2048]
  const void* wo    = d_in[8];   // [6][1024][1024]
  const void* ff_g  = d_in[9];
  const void* ff_b  = d_in[10];
  const void* w1    = d_in[11];  // [6][1024][4096]
  const void* w2    = d_in[12];  // [6][4096][1024]
  const void* fin_g = d_in[13];
  const void* fin_b = d_in[14];

  // --- workspace carve (runtime-adaptive; deterministic given ws_size) ---
  const size_t MB = 1024ull * 1024ull;
  char* w = (char*)d_ws;
  int*   flag = (int*)w;    w += 1 * MB;   // dtype flag
  float* lat  = (float*)w;  w += 8 * MB;   // residual stream fp32 [2048][1024]
  u16*   lnl  = (u16*)w;    w += 4 * MB;   // LN(lat); reused as LN pre-FF
  u16*   qbuf = (u16*)w;    w += 4 * MB;   // q [2048][1024]
  u16*   ao   = (u16*)w;    w += 4 * MB;   // attention out [2048][1024]
  u16*   kvl  = (u16*)w;    w += 8 * MB;   // latent k|v [2048][2048]
  u16*   h1   = (u16*)w;    w += 16 * MB;  // gelu(lat@w1) [2048][4096]
  const size_t base = 45 * MB;
  int CH = 32;  // media chunk: CH groups at a time; 6 MiB per group
  while (CH > 1 && base + (size_t)CH * 6 * MB > ws_size) CH >>= 1;
  u16* xn  = (u16*)w;  w += (size_t)CH * 2 * MB;  // LN(x) chunk
  u16* kvm = (u16*)w;                             // media k|v [CH*1024][2048]
  const int nch = 32 / CH;

  detect_kernel<<<1, 64, 0, stream>>>((const u16*)x, flag);
  init_lat_kernel<<<2048, 256, 0, stream>>>(lats, lat, flag);

  for (int i = 0; i < 6; ++i) {
    ln_kernel<1, 0><<<2048, 256, 0, stream>>>(
        lat, 0, nl_g, nl_b, (long)i * 1024, lnl, flag);
    gemm_kernel<0><<<dim3(16, 8), 256, 0, stream>>>(
        lnl, wq, (long)i * 1024 * 1024, qbuf, nullptr, 2048, 1024, 1024, flag);
    gemm_kernel<0><<<dim3(16, 16), 256, 0, stream>>>(
        lnl, wkv, (long)i * 1024 * 2048, kvl, nullptr, 2048, 2048, 1024, flag);
    for (int c = 0; c < nch; ++c) {
      ln_kernel<0, 0><<<CH * 1024, 256, 0, stream>>>(
          x, (long)c * CH * 1024 * 1024, nm_g, nm_b, (long)i * 1024, xn, flag);
      gemm_kernel<0><<<dim3(CH * 8, 16), 256, 0, stream>>>(
          xn, wkv, (long)i * 1024 * 2048, kvm, nullptr, CH * 1024, 2048, 1024, flag);
      attn_kernel<<<dim3(CH, 16), 256, 0, stream>>>(qbuf, kvm, kvl, ao, c * CH);
    }
    gemm_kernel<2><<<dim3(16, 8), 256, 0, stream>>>(
        ao, wo, (long)i * 1024 * 1024, lat, lat, 2048, 1024, 1024, flag);
    ln_kernel<1, 0><<<2048, 256, 0, stream>>>(
        lat, 0, ff_g, ff_b, (long)i * 1024, lnl, flag);
    gemm_kernel<1><<<dim3(16, 32), 256, 0, stream>>>(
        lnl, w1, (long)i * 1024 * 4096, h1, nullptr, 2048, 4096, 1024, flag);
    gemm_kernel<2><<<dim3(16, 8), 256, 0, stream>>>(
        h1, w2, (long)i * 4096 * 1024, lat, lat, 2048, 1024, 4096, flag);
  }
  ln_kernel<1, 1><<<2048, 256, 0, stream>>>(
      lat, 0, fin_g, fin_b, 0, d_out, flag);
}

// Round 3
// 4286.185 us; speedup vs baseline: 8.5065x; 8.5065x over previous
//
#include <hip/hip_runtime.h>

// ============================================================================
// Perceiver Resampler. Interface dtype auto-detected (fp32 vs bf16) at
// runtime from the bit pattern of x; internal compute bf16 MFMA + fp32
// accum/residual. B*T = 32 groups, 1024 media tokens, 64 latents, D=1024.
// ============================================================================

typedef unsigned short u16;  // raw bf16 bits
typedef __attribute__((ext_vector_type(8))) short short8;
typedef __attribute__((ext_vector_type(4))) float f32x4;

__device__ __forceinline__ float bf2f(u16 u) {
  return __uint_as_float(((unsigned)u) << 16);
}
__device__ __forceinline__ u16 f2bf(float f) {
  unsigned u = __float_as_uint(f);
  unsigned r = (u + 0x7FFFu + ((u >> 16) & 1u)) >> 16;  // RNE
  return (u16)r;
}

// ---------------------------------------------------------------------------
// Dtype detector: bf16 N(0,1) data has exponent field in [115,133] at even
// u16 indices; fp32 data's even u16s are mantissa bits (uniform exponent).
// flag=1 -> interface arrays are bf16; flag=0 -> fp32.
// ---------------------------------------------------------------------------
__global__ void detect_kernel(const u16* __restrict__ x, int* __restrict__ flag) {
  int lane = threadIdx.x;  // 64 threads
  u16 u = x[2 * lane];
  int e = (u >> 7) & 0xFF;
  unsigned long long b = __ballot(e >= 115 && e <= 133);
  if (lane == 0) flag[0] = (__popcll(b) >= 40) ? 1 : 0;
}

// ---------------------------------------------------------------------------
// GEMM: C[M,N] = A[M,K] @ B[K,N]; A bf16 row-major; B bf16 or fp32 (flag).
// EPI 0: store bf16. EPI 1: exact GELU -> bf16. EPI 2: fp32 store + residual R.
// 128x128 block tile, 4 waves 2x2, each wave 64x64 via 4x4 mfma 16x16x32.
// B transposed on the GLOBAL-read side (K-strided coalesced loads, one
// ds_write_b128 per 8 elems) -- LDS-side u16 scatter was a 16-way bank
// conflict. Pad 74 u16 = 37 words (odd) -> vector ops spread across banks.
// MFMA operands SWAPPED (mfma(b,a)): lane then holds 4 consecutive-N
// elements of one C row -> ushort4/float4 vectorized epilogue stores.
// (Round-2 lesson: occupancy 4/CU + XCD swizzle blew the per-XCD C-tile
// working set past L2 -> partial-line write RMW storm, WRITE 131MB->7.5GB.
// Keep 2/CU, natural dispatch order, wide stores.)
// ---------------------------------------------------------------------------
template <int EPI>
__global__ __launch_bounds__(256, 2)
void gemm_kernel(const u16* __restrict__ A, const void* __restrict__ Bv,
                 long Boff, void* __restrict__ Cp, const float* __restrict__ R,
                 int M, int N, int K, const int* __restrict__ flag) {
  __shared__ u16 As[128][74];
  __shared__ u16 Bs[128][74];  // Bs[n][k] (transposed)

  const int isb = *flag;
  const u16*   B16 = (const u16*)Bv + Boff;
  const float* B32 = (const float*)Bv + Boff;

  const int tid  = threadIdx.x;
  const int lane = tid & 63;
  const int wave = tid >> 6;
  const int wm = (wave >> 1) * 64;
  const int wn = (wave & 1) * 64;
  const int r  = lane & 15;
  const int qd = lane >> 4;

  const long bm = (long)blockIdx.x * 128;
  const long bn = (long)blockIdx.y * 128;

  f32x4 acc[4][4];
#pragma unroll
  for (int i = 0; i < 4; ++i)
#pragma unroll
    for (int j = 0; j < 4; ++j) acc[i][j] = (f32x4){0.f, 0.f, 0.f, 0.f};

  const int ra = tid >> 3, ca = (tid & 7) * 8;   // A stage
  const int nb = tid & 127;                      // B stage: column within tile
  const int kh2 = tid >> 7;                      // 0..1: which 8-k chunk
  const u16* Aptr = A + (bm + ra) * (long)K + ca;

  for (int k0 = 0; k0 < K; k0 += 64) {
#pragma unroll
    for (int it = 0; it < 4; ++it) {  // A tile 128x64
      int4 av = *(const int4*)(Aptr + (long)(it * 32) * K + k0);
      *(int4*)(&As[ra + it * 32][ca]) = av;
    }
    if (isb) {
#pragma unroll
      for (int it = 0; it < 4; ++it) {  // B tile 64x128 (bf16): K-strided
        const int kb = it * 16 + kh2 * 8;
        const u16* bp = B16 + (long)(k0 + kb) * N + bn + nb;
        union { u16 u[8]; int4 v; } t;
#pragma unroll
        for (int j = 0; j < 8; ++j) t.u[j] = bp[(long)j * N];
        *(int4*)&Bs[nb][kb] = t.v;
      }
    } else {
#pragma unroll
      for (int it = 0; it < 4; ++it) {  // B tile 64x128 (fp32): K-strided + cvt
        const int kb = it * 16 + kh2 * 8;
        const float* bp = B32 + (long)(k0 + kb) * N + bn + nb;
        union { u16 u[8]; int4 v; } t;
#pragma unroll
        for (int j = 0; j < 8; ++j) t.u[j] = f2bf(bp[(long)j * N]);
        *(int4*)&Bs[nb][kb] = t.v;
      }
    }
    __syncthreads();

#pragma unroll
    for (int kh = 0; kh < 2; ++kh) {
      short8 af[4], bfv[4];
#pragma unroll
      for (int mt = 0; mt < 4; ++mt)
        af[mt] = *(const short8*)(&As[wm + mt * 16 + r][kh * 32 + qd * 8]);
#pragma unroll
      for (int nt = 0; nt < 4; ++nt)
        bfv[nt] = *(const short8*)(&Bs[wn + nt * 16 + r][kh * 32 + qd * 8]);
      // operands swapped: D = Bt-frag x A-frag -> lane holds C[m=r][n=qd*4+i]
#pragma unroll
      for (int mt = 0; mt < 4; ++mt)
#pragma unroll
        for (int nt = 0; nt < 4; ++nt)
          acc[mt][nt] = __builtin_amdgcn_mfma_f32_16x16x32_bf16(
              bfv[nt], af[mt], acc[mt][nt], 0, 0, 0);
    }
    __syncthreads();
  }

  // Swapped C/D layout: lane(r,qd) holds C[bm+wm+mt*16+r][bn+wn+nt*16+qd*4+i]
  // -> 4 consecutive N elems per lane: vectorized 8B/16B stores.
#pragma unroll
  for (int mt = 0; mt < 4; ++mt) {
    const long row = bm + wm + mt * 16 + r;
#pragma unroll
    for (int nt = 0; nt < 4; ++nt) {
      const long col = bn + wn + nt * 16 + qd * 4;
      const long idx = row * N + col;
      if (EPI == 0) {
        ushort4 o;
        o.x = f2bf(acc[mt][nt][0]); o.y = f2bf(acc[mt][nt][1]);
        o.z = f2bf(acc[mt][nt][2]); o.w = f2bf(acc[mt][nt][3]);
        *(ushort4*)((u16*)Cp + idx) = o;
      } else if (EPI == 1) {
        ushort4 o;
        float v0 = acc[mt][nt][0], v1 = acc[mt][nt][1];
        float v2 = acc[mt][nt][2], v3 = acc[mt][nt][3];
        o.x = f2bf(0.5f * v0 * (1.0f + erff(v0 * 0.70710678118654752f)));
        o.y = f2bf(0.5f * v1 * (1.0f + erff(v1 * 0.70710678118654752f)));
        o.z = f2bf(0.5f * v2 * (1.0f + erff(v2 * 0.70710678118654752f)));
        o.w = f2bf(0.5f * v3 * (1.0f + erff(v3 * 0.70710678118654752f)));
        *(ushort4*)((u16*)Cp + idx) = o;
      } else {
        float4 rv = *(const float4*)(R + idx);
        float4 o;
        o.x = acc[mt][nt][0] + rv.x; o.y = acc[mt][nt][1] + rv.y;
        o.z = acc[mt][nt][2] + rv.z; o.w = acc[mt][nt][3] + rv.w;
        *(float4*)((float*)Cp + idx) = o;
      }
    }
  }
}

// ---------------------------------------------------------------------------
// LayerNorm over last dim (1024). One block (256 thr) per row.
// INMODE 0: input dtype follows flag (d_in array). INMODE 1: input fp32 (lat).
// OUTMODE 0: bf16 out (internal). OUTMODE 1: out dtype follows flag (d_out).
// gamma/beta are d_in arrays -> dtype follows flag.
// ---------------------------------------------------------------------------
template <int INMODE, int OUTMODE>
__global__ __launch_bounds__(256)
void ln_kernel(const void* __restrict__ inp, long ioff,
               const void* __restrict__ gam, const void* __restrict__ bet,
               long goff, void* __restrict__ outp, const int* __restrict__ flag) {
  const int isb = *flag;
  const long row = blockIdx.x;
  const int tid = threadIdx.x;
  float x0, x1, x2, x3;
  const bool in_f32 = (INMODE == 1) || (!isb);
  if (in_f32) {
    float4 v = *((const float4*)((const float*)inp + ioff + row * 1024) + tid);
    x0 = v.x; x1 = v.y; x2 = v.z; x3 = v.w;
  } else {
    ushort4 u = *((const ushort4*)((const u16*)inp + ioff + row * 1024) + tid);
    x0 = bf2f(u.x); x1 = bf2f(u.y); x2 = bf2f(u.z); x3 = bf2f(u.w);
  }
  float s1 = x0 + x1 + x2 + x3;
  float s2 = x0 * x0 + x1 * x1 + x2 * x2 + x3 * x3;
#pragma unroll
  for (int off = 32; off >= 1; off >>= 1) {
    s1 += __shfl_xor(s1, off);
    s2 += __shfl_xor(s2, off);
  }
  __shared__ float r1[4], r2[4];
  if ((tid & 63) == 0) { r1[tid >> 6] = s1; r2[tid >> 6] = s2; }
  __syncthreads();
  s1 = r1[0] + r1[1] + r1[2] + r1[3];
  s2 = r2[0] + r2[1] + r2[2] + r2[3];
  const float mean = s1 * (1.0f / 1024.0f);
  const float var  = s2 * (1.0f / 1024.0f) - mean * mean;
  const float rstd = rsqrtf(var + 1e-5f);
  float g0, g1, g2, g3, b0, b1, b2, b3;
  if (isb) {
    ushort4 ug = *((const ushort4*)((const u16*)gam + goff) + tid);
    ushort4 ub = *((const ushort4*)((const u16*)bet + goff) + tid);
    g0 = bf2f(ug.x); g1 = bf2f(ug.y); g2 = bf2f(ug.z); g3 = bf2f(ug.w);
    b0 = bf2f(ub.x); b1 = bf2f(ub.y); b2 = bf2f(ub.z); b3 = bf2f(ub.w);
  } else {
    float4 vg = *((const float4*)((const float*)gam + goff) + tid);
    float4 vb = *((const float4*)((const float*)bet + goff) + tid);
    g0 = vg.x; g1 = vg.y; g2 = vg.z; g3 = vg.w;
    b0 = vb.x; b1 = vb.y; b2 = vb.z; b3 = vb.w;
  }
  float o0 = (x0 - mean) * rstd * g0 + b0;
  float o1 = (x1 - mean) * rstd * g1 + b1;
  float o2 = (x2 - mean) * rstd * g2 + b2;
  float o3 = (x3 - mean) * rstd * g3 + b3;
  const bool out_f32 = (OUTMODE == 1) && (!isb);
  if (out_f32) {
    float4 o = {o0, o1, o2, o3};
    *((float4*)((float*)outp + row * 1024) + tid) = o;
  } else {
    ushort4 o;
    o.x = f2bf(o0); o.y = f2bf(o1); o.z = f2bf(o2); o.w = f2bf(o3);
    *((ushort4*)((u16*)outp + row * 1024) + tid) = o;
  }
}

// ---------------------------------------------------------------------------
// lat[g][n][d] = latents[n][d] (fp32), g=0..31
// ---------------------------------------------------------------------------
__global__ __launch_bounds__(256)
void init_lat_kernel(const void* __restrict__ latents, float* __restrict__ lat,
                     const int* __restrict__ flag) {
  const int isb = *flag;
  long i = (long)blockIdx.x * 256 + threadIdx.x;  // one thread per 4 elems
  long src = (4 * i) & 65535;
  float4 o;
  if (isb) {
    ushort4 u = *(const ushort4*)((const u16*)latents + src);
    o = (float4){bf2f(u.x), bf2f(u.y), bf2f(u.z), bf2f(u.w)};
  } else {
    o = *(const float4*)((const float*)latents + src);
  }
  *(float4*)(lat + 4 * i) = o;
}

// ---------------------------------------------------------------------------
// Attention (MFMA flash): one block per (local g, h). 64 queries, 1088 keys
// in 17 tiles of 64. 4 waves x 16 query rows each. bf16 MFMA 16x16x32 for
// QK^T and PV; online softmax in registers (16-lane shfl reduces); P staged
// through LDS (reusing the Q buffer; Q hoisted to registers); V staged
// transposed for the PV B-fragment.
// ---------------------------------------------------------------------------
__global__ __launch_bounds__(256, 2)
void attn_kernel(const u16* __restrict__ Q, const u16* __restrict__ KVM,
                 const u16* __restrict__ KVL, u16* __restrict__ O, int g0) {
  const int gl = blockIdx.x;
  const int g  = g0 + gl;
  const int h  = blockIdx.y;
  __shared__ u16 k_s[64][72];    // K tile, row-major [j][d]
  __shared__ u16 vt_s[64][72];   // V tile transposed [d][j]
  __shared__ u16 qp_s[64][72];   // Q tile, then reused as bf16 P tile [q][j]

  const int tid  = threadIdx.x;
  const int lane = tid & 63;
  const int wave = tid >> 6;
  const int r  = lane & 15;
  const int qd = lane >> 4;
  const int qr = wave * 16;      // this wave's query-row base

  {  // stage Q (bf16, unscaled; 0.125 scale folded into softmax)
    const int rr = tid >> 2, cc = (tid & 3) * 16;
    const u16* qp = Q + ((long)g * 64 + rr) * 1024 + h * 64 + cc;
    *(int4*)&qp_s[rr][cc]     = *(const int4*)qp;
    *(int4*)&qp_s[rr][cc + 8] = *(const int4*)(qp + 8);
  }
  __syncthreads();

  // Q A-fragments live in registers for all 17 tiles (qp_s becomes P below)
  short8 aq0 = *(const short8*)&qp_s[qr + r][qd * 8];
  short8 aq1 = *(const short8*)&qp_s[qr + r][32 + qd * 8];

  f32x4 acc_o[4];
  float m0[4], l0[4];
#pragma unroll
  for (int i = 0; i < 4; ++i) {
    m0[i] = -3.0e38f;
    l0[i] = 0.f;
    acc_o[i] = (f32x4){0.f, 0.f, 0.f, 0.f};
  }

  for (int t = 0; t < 17; ++t) {
    const u16* base = (t < 16)
        ? KVM + ((long)gl * 1024 + t * 64) * 2048 + h * 64
        : KVL + ((long)g * 64) * 2048 + h * 64;
    {  // K tile 64x64 row-major, vector copy
      const int rr = tid >> 2, cc = (tid & 3) * 16;
      const u16* kp = base + (long)rr * 2048 + cc;
      *(int4*)&k_s[rr][cc]     = *(const int4*)kp;
      *(int4*)&k_s[rr][cc + 8] = *(const int4*)(kp + 8);
    }
    {  // V tile transposed: vt_s[d][j] = V[j][d]; coalesced 2B/lane loads,
       // contiguous-j register accumulate -> 2x b128 LDS writes
      const int d = lane;
      const u16* vp = base + 1024 + (long)(wave * 16) * 2048 + d;
      union { u16 u[16]; int4 v[2]; } tmp;
#pragma unroll
      for (int u = 0; u < 16; ++u) tmp.u[u] = vp[(long)u * 2048];
      *(int4*)&vt_s[d][wave * 16]     = tmp.v[0];
      *(int4*)&vt_s[d][wave * 16 + 8] = tmp.v[1];
    }
    __syncthreads();

    // --- S = Q @ K^T (wave rows qr..qr+15, cols 0..63) ---
    f32x4 sac[4];
#pragma unroll
    for (int nt = 0; nt < 4; ++nt) sac[nt] = (f32x4){0.f, 0.f, 0.f, 0.f};
#pragma unroll
    for (int nt = 0; nt < 4; ++nt) {
      short8 b0 = *(const short8*)&k_s[nt * 16 + r][qd * 8];
      short8 b1 = *(const short8*)&k_s[nt * 16 + r][32 + qd * 8];
      sac[nt] = __builtin_amdgcn_mfma_f32_16x16x32_bf16(aq0, b0, sac[nt], 0, 0, 0);
      sac[nt] = __builtin_amdgcn_mfma_f32_16x16x32_bf16(aq1, b1, sac[nt], 0, 0, 0);
    }

    // --- online softmax; lane's rows are qr+qd*4+i, cols nt*16+r ---
    float pr[4][4];
#pragma unroll
    for (int nt = 0; nt < 4; ++nt)
#pragma unroll
      for (int i = 0; i < 4; ++i) pr[nt][i] = sac[nt][i] * 0.125f;

#pragma unroll
    for (int i = 0; i < 4; ++i) {
      float mt = fmaxf(fmaxf(pr[0][i], pr[1][i]), fmaxf(pr[2][i], pr[3][i]));
      mt = fmaxf(mt, __shfl_xor(mt, 1));
      mt = fmaxf(mt, __shfl_xor(mt, 2));
      mt = fmaxf(mt, __shfl_xor(mt, 4));
      mt = fmaxf(mt, __shfl_xor(mt, 8));
      float mn = fmaxf(m0[i], mt);
      float al = __expf(m0[i] - mn);
      m0[i] = mn;
      float ts = 0.f;
#pragma unroll
      for (int nt = 0; nt < 4; ++nt) {
        float p = __expf(pr[nt][i] - mn);
        pr[nt][i] = p;
        ts += p;
      }
      ts += __shfl_xor(ts, 1);
      ts += __shfl_xor(ts, 2);
      ts += __shfl_xor(ts, 4);
      ts += __shfl_xor(ts, 8);
      l0[i] = l0[i] * al + ts;
#pragma unroll
      for (int nt = 0; nt < 4; ++nt) acc_o[nt][i] *= al;
    }

    // P -> bf16 into qp_s (each wave writes only its own 16 rows)
#pragma unroll
    for (int nt = 0; nt < 4; ++nt)
#pragma unroll
      for (int i = 0; i < 4; ++i)
        qp_s[qr + qd * 4 + i][nt * 16 + r] = f2bf(pr[nt][i]);

    // --- O += P @ V ---
    short8 ap0 = *(const short8*)&qp_s[qr + r][qd * 8];
    short8 ap1 = *(const short8*)&qp_s[qr + r][32 + qd * 8];
#pragma unroll
    for (int nt = 0; nt < 4; ++nt) {
      short8 b0 = *(const short8*)&vt_s[nt * 16 + r][qd * 8];
      short8 b1 = *(const short8*)&vt_s[nt * 16 + r][32 + qd * 8];
      acc_o[nt] = __builtin_amdgcn_mfma_f32_16x16x32_bf16(ap0, b0, acc_o[nt], 0, 0, 0);
      acc_o[nt] = __builtin_amdgcn_mfma_f32_16x16x32_bf16(ap1, b1, acc_o[nt], 0, 0, 0);
    }
    __syncthreads();
  }

  // epilogue: O row = g*64 + qr + qd*4 + i, col = h*64 + nt*16 + r
#pragma unroll
  for (int i = 0; i < 4; ++i) {
    float inv = 1.0f / l0[i];
    long row = (long)g * 64 + qr + qd * 4 + i;
#pragma unroll
    for (int nt = 0; nt < 4; ++nt)
      O[row * 1024 + h * 64 + nt * 16 + r] = f2bf(acc_o[nt][i] * inv);
  }
}

// ---------------------------------------------------------------------------
extern "C" void kernel_launch(void* const* d_in, const int* in_sizes, int n_in,
                              void* d_out, int out_size, void* d_ws, size_t ws_size,
                              hipStream_t stream) {
  const void* x     = d_in[0];   // [32][1024][1024]
  const void* lats  = d_in[1];   // [64][1024]
  const void* nm_g  = d_in[2];
  const void* nm_b  = d_in[3];
  const void* nl_g  = d_in[4];
  const void* nl_b  = d_in[5];
  const void* wq    = d_in[6];   // [6][1024][1024]
  const void* wkv   = d_in[7];   // [6][1024][2048]
  const void* wo    = d_in[8];   // [6][1024][1024]
  const void* ff_g  = d_in[9];
  const void* ff_b  = d_in[10];
  const void* w1    = d_in[11];  // [6][1024][4096]
  const void* w2    = d_in[12];  // [6][4096][1024]
  const void* fin_g = d_in[13];
  const void* fin_b = d_in[14];

  // --- workspace carve (runtime-adaptive; deterministic given ws_size) ---
  const size_t MB = 1024ull * 1024ull;
  char* w = (char*)d_ws;
  int*   flag = (int*)w;    w += 1 * MB;   // dtype flag
  float* lat  = (float*)w;  w += 8 * MB;   // residual stream fp32 [2048][1024]
  u16*   lnl  = (u16*)w;    w += 4 * MB;   // LN(lat); reused as LN pre-FF
  u16*   qbuf = (u16*)w;    w += 4 * MB;   // q [2048][1024]
  u16*   ao   = (u16*)w;    w += 4 * MB;   // attention out [2048][1024]
  u16*   kvl  = (u16*)w;    w += 8 * MB;   // latent k|v [2048][2048]
  u16*   h1   = (u16*)w;    w += 16 * MB;  // gelu(lat@w1) [2048][4096]
  const size_t base = 45 * MB;
  int CH = 32;  // media chunk: CH groups at a time; 6 MiB per group
  while (CH > 1 && base + (size_t)CH * 6 * MB > ws_size) CH >>= 1;
  u16* xn  = (u16*)w;  w += (size_t)CH * 2 * MB;  // LN(x) chunk
  u16* kvm = (u16*)w;                             // media k|v [CH*1024][2048]
  const int nch = 32 / CH;

  detect_kernel<<<1, 64, 0, stream>>>((const u16*)x, flag);
  init_lat_kernel<<<2048, 256, 0, stream>>>(lats, lat, flag);

  for (int i = 0; i < 6; ++i) {
    ln_kernel<1, 0><<<2048, 256, 0, stream>>>(
        lat, 0, nl_g, nl_b, (long)i * 1024, lnl, flag);
    gemm_kernel<0><<<dim3(16, 8), 256, 0, stream>>>(
        lnl, wq, (long)i * 1024 * 1024, qbuf, nullptr, 2048, 1024, 1024, flag);
    gemm_kernel<0><<<dim3(16, 16), 256, 0, stream>>>(
        lnl, wkv, (long)i * 1024 * 2048, kvl, nullptr, 2048, 2048, 1024, flag);
    for (int c = 0; c < nch; ++c) {
      ln_kernel<0, 0><<<CH * 1024, 256, 0, stream>>>(
          x, (long)c * CH * 1024 * 1024, nm_g, nm_b, (long)i * 1024, xn, flag);
      gemm_kernel<0><<<dim3(CH * 8, 16), 256, 0, stream>>>(
          xn, wkv, (long)i * 1024 * 2048, kvm, nullptr, CH * 1024, 2048, 1024, flag);
      attn_kernel<<<dim3(CH, 16), 256, 0, stream>>>(qbuf, kvm, kvl, ao, c * CH);
    }
    gemm_kernel<2><<<dim3(16, 8), 256, 0, stream>>>(
        ao, wo, (long)i * 1024 * 1024, lat, lat, 2048, 1024, 1024, flag);
    ln_kernel<1, 0><<<2048, 256, 0, stream>>>(
        lat, 0, ff_g, ff_b, (long)i * 1024, lnl, flag);
    gemm_kernel<1><<<dim3(16, 32), 256, 0, stream>>>(
        lnl, w1, (long)i * 1024 * 4096, h1, nullptr, 2048, 4096, 1024, flag);
    gemm_kernel<2><<<dim3(16, 8), 256, 0, stream>>>(
        h1, w2, (long)i * 4096 * 1024, lat, lat, 2048, 1024, 4096, flag);
  }
  ln_kernel<1, 1><<<2048, 256, 0, stream>>>(
      lat, 0, fin_g, fin_b, 0, d_out, flag);
}

// Round 5
// 3502.533 us; speedup vs baseline: 10.4098x; 1.2237x over previous
//
#include <hip/hip_runtime.h>

// ============================================================================
// Perceiver Resampler. Interface dtype auto-detected (fp32 vs bf16) at
// runtime from the bit pattern of x; internal compute bf16 MFMA + fp32
// accum/residual. B*T = 32 groups, 1024 media tokens, 64 latents, D=1024.
// (Resubmission of round-4 kernel: bench infra failed, no code defect found.)
// ============================================================================

typedef unsigned short u16;  // raw bf16 bits
typedef __attribute__((ext_vector_type(8))) short short8;
typedef __attribute__((ext_vector_type(4))) float f32x4;

__device__ __forceinline__ float bf2f(u16 u) {
  return __uint_as_float(((unsigned)u) << 16);
}
__device__ __forceinline__ u16 f2bf(float f) {
  unsigned u = __float_as_uint(f);
  unsigned r = (u + 0x7FFFu + ((u >> 16) & 1u)) >> 16;  // RNE
  return (u16)r;
}

// ---------------------------------------------------------------------------
// Dtype detector: bf16 N(0,1) data has exponent field in [115,133] at even
// u16 indices; fp32 data's even u16s are mantissa bits (uniform exponent).
// flag=1 -> interface arrays are bf16; flag=0 -> fp32.
// ---------------------------------------------------------------------------
__global__ void detect_kernel(const u16* __restrict__ x, int* __restrict__ flag) {
  int lane = threadIdx.x;  // 64 threads
  u16 u = x[2 * lane];
  int e = (u >> 7) & 0xFF;
  unsigned long long b = __ballot(e >= 115 && e <= 133);
  if (lane == 0) flag[0] = (__popcll(b) >= 40) ? 1 : 0;
}

// ---------------------------------------------------------------------------
// Weight transpose+convert: W[K][N] (fp32 or bf16 per flag) -> Wt[N][K] bf16.
// 64x64 tile via LDS. One-time per layer; pulls all f2bf + K-strided loads
// out of the GEMM hot loop (GEMM B-stage was 37% VALUBusy from this).
// ---------------------------------------------------------------------------
__global__ __launch_bounds__(256)
void wtrans_kernel(const void* __restrict__ W, long woff, u16* __restrict__ Wt,
                   int K, int N, const int* __restrict__ flag) {
  const int isb = *flag;
  __shared__ u16 t[64][72];
  const long k0 = (long)blockIdx.x * 64;
  const long n0 = (long)blockIdx.y * 64;
  const int tr = threadIdx.x >> 2;        // 0..63
  const int tc = (threadIdx.x & 3) * 16;  // 0,16,32,48
  if (isb) {
    const u16* src = (const u16*)W + woff + (k0 + tr) * N + n0 + tc;
    *(int4*)&t[tr][tc]     = *(const int4*)src;
    *(int4*)&t[tr][tc + 8] = *(const int4*)(src + 8);
  } else {
    const float* src = (const float*)W + woff + (k0 + tr) * N + n0 + tc;
    float4 f0 = *(const float4*)(src);
    float4 f1 = *(const float4*)(src + 4);
    float4 f2 = *(const float4*)(src + 8);
    float4 f3 = *(const float4*)(src + 12);
    u16 tmp[16] = {f2bf(f0.x), f2bf(f0.y), f2bf(f0.z), f2bf(f0.w),
                   f2bf(f1.x), f2bf(f1.y), f2bf(f1.z), f2bf(f1.w),
                   f2bf(f2.x), f2bf(f2.y), f2bf(f2.z), f2bf(f2.w),
                   f2bf(f3.x), f2bf(f3.y), f2bf(f3.z), f2bf(f3.w)};
    *(int4*)&t[tr][tc]     = *(int4*)&tmp[0];
    *(int4*)&t[tr][tc + 8] = *(int4*)&tmp[8];
  }
  __syncthreads();
  u16 o[16];
#pragma unroll
  for (int j = 0; j < 16; ++j) o[j] = t[tc + j][tr];
  u16* dst = Wt + (n0 + tr) * (long)K + k0 + tc;
  *(int4*)dst       = *(int4*)&o[0];
  *(int4*)(dst + 8) = *(int4*)&o[8];
}

// ---------------------------------------------------------------------------
// GEMM: C[M,N] = A[M,K] @ Bt[N,K]^T; A, Bt bf16 row-major (Bt pre-transposed
// by wtrans_kernel -> B-stage is 4 int4 loads, same as A; no cvt, no stride).
// EPI 0: store bf16. EPI 1: exact GELU -> bf16. EPI 2: fp32 store + residual R.
// 128x128 block tile, 4 waves 2x2, each wave 64x64 via 4x4 mfma 16x16x32.
// Pad 74 u16 = 37 words (odd) -> vector LDS ops spread across banks.
// MFMA operands SWAPPED (mfma(b,a)): lane holds 4 consecutive-N elements of
// one C row -> ushort4/float4 vectorized epilogue stores (r2 lesson: scalar
// C stores -> partial-line RMW storm when C tiles outrun L2).
// ---------------------------------------------------------------------------
template <int EPI>
__global__ __launch_bounds__(256, 2)
void gemm_kernel(const u16* __restrict__ A, const u16* __restrict__ Bt,
                 void* __restrict__ Cp, const float* __restrict__ R,
                 int M, int N, int K) {
  __shared__ u16 As[128][74];
  __shared__ u16 Bs[128][74];  // Bs[n][k]

  const int tid  = threadIdx.x;
  const int lane = tid & 63;
  const int wave = tid >> 6;
  const int wm = (wave >> 1) * 64;
  const int wn = (wave & 1) * 64;
  const int r  = lane & 15;
  const int qd = lane >> 4;

  const long bm = (long)blockIdx.x * 128;
  const long bn = (long)blockIdx.y * 128;

  f32x4 acc[4][4];
#pragma unroll
  for (int i = 0; i < 4; ++i)
#pragma unroll
    for (int j = 0; j < 4; ++j) acc[i][j] = (f32x4){0.f, 0.f, 0.f, 0.f};

  const int ra = tid >> 3, ca = (tid & 7) * 8;  // stage: 32 rows x 64 k / iter
  const u16* Aptr = A  + (bm + ra) * (long)K + ca;
  const u16* Bptr = Bt + (bn + ra) * (long)K + ca;

  for (int k0 = 0; k0 < K; k0 += 64) {
#pragma unroll
    for (int it = 0; it < 4; ++it) {  // A tile 128x64
      int4 av = *(const int4*)(Aptr + (long)(it * 32) * K + k0);
      *(int4*)(&As[ra + it * 32][ca]) = av;
    }
#pragma unroll
    for (int it = 0; it < 4; ++it) {  // B tile 128x64 (pre-transposed)
      int4 bv = *(const int4*)(Bptr + (long)(it * 32) * K + k0);
      *(int4*)(&Bs[ra + it * 32][ca]) = bv;
    }
    __syncthreads();

#pragma unroll
    for (int kh = 0; kh < 2; ++kh) {
      short8 af[4], bfv[4];
#pragma unroll
      for (int mt = 0; mt < 4; ++mt)
        af[mt] = *(const short8*)(&As[wm + mt * 16 + r][kh * 32 + qd * 8]);
#pragma unroll
      for (int nt = 0; nt < 4; ++nt)
        bfv[nt] = *(const short8*)(&Bs[wn + nt * 16 + r][kh * 32 + qd * 8]);
      // operands swapped: D = Bt-frag x A-frag -> lane holds C[m=r][n=qd*4+i]
#pragma unroll
      for (int mt = 0; mt < 4; ++mt)
#pragma unroll
        for (int nt = 0; nt < 4; ++nt)
          acc[mt][nt] = __builtin_amdgcn_mfma_f32_16x16x32_bf16(
              bfv[nt], af[mt], acc[mt][nt], 0, 0, 0);
    }
    __syncthreads();
  }

  // Swapped C/D layout: lane(r,qd) holds C[bm+wm+mt*16+r][bn+wn+nt*16+qd*4+i]
#pragma unroll
  for (int mt = 0; mt < 4; ++mt) {
    const long row = bm + wm + mt * 16 + r;
#pragma unroll
    for (int nt = 0; nt < 4; ++nt) {
      const long col = bn + wn + nt * 16 + qd * 4;
      const long idx = row * N + col;
      if (EPI == 0) {
        ushort4 o;
        o.x = f2bf(acc[mt][nt][0]); o.y = f2bf(acc[mt][nt][1]);
        o.z = f2bf(acc[mt][nt][2]); o.w = f2bf(acc[mt][nt][3]);
        *(ushort4*)((u16*)Cp + idx) = o;
      } else if (EPI == 1) {
        ushort4 o;
        float v0 = acc[mt][nt][0], v1 = acc[mt][nt][1];
        float v2 = acc[mt][nt][2], v3 = acc[mt][nt][3];
        o.x = f2bf(0.5f * v0 * (1.0f + erff(v0 * 0.70710678118654752f)));
        o.y = f2bf(0.5f * v1 * (1.0f + erff(v1 * 0.70710678118654752f)));
        o.z = f2bf(0.5f * v2 * (1.0f + erff(v2 * 0.70710678118654752f)));
        o.w = f2bf(0.5f * v3 * (1.0f + erff(v3 * 0.70710678118654752f)));
        *(ushort4*)((u16*)Cp + idx) = o;
      } else {
        float4 rv = *(const float4*)(R + idx);
        float4 o;
        o.x = acc[mt][nt][0] + rv.x; o.y = acc[mt][nt][1] + rv.y;
        o.z = acc[mt][nt][2] + rv.z; o.w = acc[mt][nt][3] + rv.w;
        *(float4*)((float*)Cp + idx) = o;
      }
    }
  }
}

// ---------------------------------------------------------------------------
// LayerNorm over last dim (1024). One block (256 thr) per row.
// INMODE 0: input dtype follows flag (d_in array). INMODE 1: input fp32 (lat).
// OUTMODE 0: bf16 out (internal). OUTMODE 1: out dtype follows flag (d_out).
// gamma/beta are d_in arrays -> dtype follows flag.
// ---------------------------------------------------------------------------
template <int INMODE, int OUTMODE>
__global__ __launch_bounds__(256)
void ln_kernel(const void* __restrict__ inp, long ioff,
               const void* __restrict__ gam, const void* __restrict__ bet,
               long goff, void* __restrict__ outp, const int* __restrict__ flag) {
  const int isb = *flag;
  const long row = blockIdx.x;
  const int tid = threadIdx.x;
  float x0, x1, x2, x3;
  const bool in_f32 = (INMODE == 1) || (!isb);
  if (in_f32) {
    float4 v = *((const float4*)((const float*)inp + ioff + row * 1024) + tid);
    x0 = v.x; x1 = v.y; x2 = v.z; x3 = v.w;
  } else {
    ushort4 u = *((const ushort4*)((const u16*)inp + ioff + row * 1024) + tid);
    x0 = bf2f(u.x); x1 = bf2f(u.y); x2 = bf2f(u.z); x3 = bf2f(u.w);
  }
  float s1 = x0 + x1 + x2 + x3;
  float s2 = x0 * x0 + x1 * x1 + x2 * x2 + x3 * x3;
#pragma unroll
  for (int off = 32; off >= 1; off >>= 1) {
    s1 += __shfl_xor(s1, off);
    s2 += __shfl_xor(s2, off);
  }
  __shared__ float r1[4], r2[4];
  if ((tid & 63) == 0) { r1[tid >> 6] = s1; r2[tid >> 6] = s2; }
  __syncthreads();
  s1 = r1[0] + r1[1] + r1[2] + r1[3];
  s2 = r2[0] + r2[1] + r2[2] + r2[3];
  const float mean = s1 * (1.0f / 1024.0f);
  const float var  = s2 * (1.0f / 1024.0f) - mean * mean;
  const float rstd = rsqrtf(var + 1e-5f);
  float g0, g1, g2, g3, b0, b1, b2, b3;
  if (isb) {
    ushort4 ug = *((const ushort4*)((const u16*)gam + goff) + tid);
    ushort4 ub = *((const ushort4*)((const u16*)bet + goff) + tid);
    g0 = bf2f(ug.x); g1 = bf2f(ug.y); g2 = bf2f(ug.z); g3 = bf2f(ug.w);
    b0 = bf2f(ub.x); b1 = bf2f(ub.y); b2 = bf2f(ub.z); b3 = bf2f(ub.w);
  } else {
    float4 vg = *((const float4*)((const float*)gam + goff) + tid);
    float4 vb = *((const float4*)((const float*)bet + goff) + tid);
    g0 = vg.x; g1 = vg.y; g2 = vg.z; g3 = vg.w;
    b0 = vb.x; b1 = vb.y; b2 = vb.z; b3 = vb.w;
  }
  float o0 = (x0 - mean) * rstd * g0 + b0;
  float o1 = (x1 - mean) * rstd * g1 + b1;
  float o2 = (x2 - mean) * rstd * g2 + b2;
  float o3 = (x3 - mean) * rstd * g3 + b3;
  const bool out_f32 = (OUTMODE == 1) && (!isb);
  if (out_f32) {
    float4 o = {o0, o1, o2, o3};
    *((float4*)((float*)outp + row * 1024) + tid) = o;
  } else {
    ushort4 o;
    o.x = f2bf(o0); o.y = f2bf(o1); o.z = f2bf(o2); o.w = f2bf(o3);
    *((ushort4*)((u16*)outp + row * 1024) + tid) = o;
  }
}

// ---------------------------------------------------------------------------
// lat[g][n][d] = latents[n][d] (fp32), g=0..31
// ---------------------------------------------------------------------------
__global__ __launch_bounds__(256)
void init_lat_kernel(const void* __restrict__ latents, float* __restrict__ lat,
                     const int* __restrict__ flag) {
  const int isb = *flag;
  long i = (long)blockIdx.x * 256 + threadIdx.x;  // one thread per 4 elems
  long src = (4 * i) & 65535;
  float4 o;
  if (isb) {
    ushort4 u = *(const ushort4*)((const u16*)latents + src);
    o = (float4){bf2f(u.x), bf2f(u.y), bf2f(u.z), bf2f(u.w)};
  } else {
    o = *(const float4*)((const float*)latents + src);
  }
  *(float4*)(lat + 4 * i) = o;
}

// ---------------------------------------------------------------------------
// Attention (MFMA flash): one block per (local g, h). 64 queries, 1088 keys
// in 17 tiles of 64. 4 waves x 16 query rows each. bf16 MFMA 16x16x32 for
// QK^T and PV; online softmax in registers (16-lane shfl reduces); P staged
// through LDS (reusing the Q buffer; Q hoisted to registers); V staged
// transposed for the PV B-fragment.
// ---------------------------------------------------------------------------
__global__ __launch_bounds__(256, 2)
void attn_kernel(const u16* __restrict__ Q, const u16* __restrict__ KVM,
                 const u16* __restrict__ KVL, u16* __restrict__ O, int g0) {
  const int gl = blockIdx.x;
  const int g  = g0 + gl;
  const int h  = blockIdx.y;
  __shared__ u16 k_s[64][72];    // K tile, row-major [j][d]
  __shared__ u16 vt_s[64][72];   // V tile transposed [d][j]
  __shared__ u16 qp_s[64][72];   // Q tile, then reused as bf16 P tile [q][j]

  const int tid  = threadIdx.x;
  const int lane = tid & 63;
  const int wave = tid >> 6;
  const int r  = lane & 15;
  const int qd = lane >> 4;
  const int qr = wave * 16;      // this wave's query-row base

  {  // stage Q (bf16, unscaled; 0.125 scale folded into softmax)
    const int rr = tid >> 2, cc = (tid & 3) * 16;
    const u16* qp = Q + ((long)g * 64 + rr) * 1024 + h * 64 + cc;
    *(int4*)&qp_s[rr][cc]     = *(const int4*)qp;
    *(int4*)&qp_s[rr][cc + 8] = *(const int4*)(qp + 8);
  }
  __syncthreads();

  // Q A-fragments live in registers for all 17 tiles (qp_s becomes P below)
  short8 aq0 = *(const short8*)&qp_s[qr + r][qd * 8];
  short8 aq1 = *(const short8*)&qp_s[qr + r][32 + qd * 8];

  f32x4 acc_o[4];
  float m0[4], l0[4];
#pragma unroll
  for (int i = 0; i < 4; ++i) {
    m0[i] = -3.0e38f;
    l0[i] = 0.f;
    acc_o[i] = (f32x4){0.f, 0.f, 0.f, 0.f};
  }

  for (int t = 0; t < 17; ++t) {
    const u16* base = (t < 16)
        ? KVM + ((long)gl * 1024 + t * 64) * 2048 + h * 64
        : KVL + ((long)g * 64) * 2048 + h * 64;
    {  // K tile 64x64 row-major, vector copy
      const int rr = tid >> 2, cc = (tid & 3) * 16;
      const u16* kp = base + (long)rr * 2048 + cc;
      *(int4*)&k_s[rr][cc]     = *(const int4*)kp;
      *(int4*)&k_s[rr][cc + 8] = *(const int4*)(kp + 8);
    }
    {  // V tile transposed: vt_s[d][j] = V[j][d]; coalesced 2B/lane loads,
       // contiguous-j register accumulate -> 2x b128 LDS writes
      const int d = lane;
      const u16* vp = base + 1024 + (long)(wave * 16) * 2048 + d;
      union { u16 u[16]; int4 v[2]; } tmp;
#pragma unroll
      for (int u = 0; u < 16; ++u) tmp.u[u] = vp[(long)u * 2048];
      *(int4*)&vt_s[d][wave * 16]     = tmp.v[0];
      *(int4*)&vt_s[d][wave * 16 + 8] = tmp.v[1];
    }
    __syncthreads();

    // --- S = Q @ K^T (wave rows qr..qr+15, cols 0..63) ---
    f32x4 sac[4];
#pragma unroll
    for (int nt = 0; nt < 4; ++nt) sac[nt] = (f32x4){0.f, 0.f, 0.f, 0.f};
#pragma unroll
    for (int nt = 0; nt < 4; ++nt) {
      short8 b0 = *(const short8*)&k_s[nt * 16 + r][qd * 8];
      short8 b1 = *(const short8*)&k_s[nt * 16 + r][32 + qd * 8];
      sac[nt] = __builtin_amdgcn_mfma_f32_16x16x32_bf16(aq0, b0, sac[nt], 0, 0, 0);
      sac[nt] = __builtin_amdgcn_mfma_f32_16x16x32_bf16(aq1, b1, sac[nt], 0, 0, 0);
    }

    // --- online softmax; lane's rows are qr+qd*4+i, cols nt*16+r ---
    float pr[4][4];
#pragma unroll
    for (int nt = 0; nt < 4; ++nt)
#pragma unroll
      for (int i = 0; i < 4; ++i) pr[nt][i] = sac[nt][i] * 0.125f;

#pragma unroll
    for (int i = 0; i < 4; ++i) {
      float mt = fmaxf(fmaxf(pr[0][i], pr[1][i]), fmaxf(pr[2][i], pr[3][i]));
      mt = fmaxf(mt, __shfl_xor(mt, 1));
      mt = fmaxf(mt, __shfl_xor(mt, 2));
      mt = fmaxf(mt, __shfl_xor(mt, 4));
      mt = fmaxf(mt, __shfl_xor(mt, 8));
      float mn = fmaxf(m0[i], mt);
      float al = __expf(m0[i] - mn);
      m0[i] = mn;
      float ts = 0.f;
#pragma unroll
      for (int nt = 0; nt < 4; ++nt) {
        float p = __expf(pr[nt][i] - mn);
        pr[nt][i] = p;
        ts += p;
      }
      ts += __shfl_xor(ts, 1);
      ts += __shfl_xor(ts, 2);
      ts += __shfl_xor(ts, 4);
      ts += __shfl_xor(ts, 8);
      l0[i] = l0[i] * al + ts;
#pragma unroll
      for (int nt = 0; nt < 4; ++nt) acc_o[nt][i] *= al;
    }

    // P -> bf16 into qp_s (each wave writes only its own 16 rows)
#pragma unroll
    for (int nt = 0; nt < 4; ++nt)
#pragma unroll
      for (int i = 0; i < 4; ++i)
        qp_s[qr + qd * 4 + i][nt * 16 + r] = f2bf(pr[nt][i]);

    // --- O += P @ V ---
    short8 ap0 = *(const short8*)&qp_s[qr + r][qd * 8];
    short8 ap1 = *(const short8*)&qp_s[qr + r][32 + qd * 8];
#pragma unroll
    for (int nt = 0; nt < 4; ++nt) {
      short8 b0 = *(const short8*)&vt_s[nt * 16 + r][qd * 8];
      short8 b1 = *(const short8*)&vt_s[nt * 16 + r][32 + qd * 8];
      acc_o[nt] = __builtin_amdgcn_mfma_f32_16x16x32_bf16(ap0, b0, acc_o[nt], 0, 0, 0);
      acc_o[nt] = __builtin_amdgcn_mfma_f32_16x16x32_bf16(ap1, b1, acc_o[nt], 0, 0, 0);
    }
    __syncthreads();
  }

  // epilogue: O row = g*64 + qr + qd*4 + i, col = h*64 + nt*16 + r
#pragma unroll
  for (int i = 0; i < 4; ++i) {
    float inv = 1.0f / l0[i];
    long row = (long)g * 64 + qr + qd * 4 + i;
#pragma unroll
    for (int nt = 0; nt < 4; ++nt)
      O[row * 1024 + h * 64 + nt * 16 + r] = f2bf(acc_o[nt][i] * inv);
  }
}

// ---------------------------------------------------------------------------
extern "C" void kernel_launch(void* const* d_in, const int* in_sizes, int n_in,
                              void* d_out, int out_size, void* d_ws, size_t ws_size,
                              hipStream_t stream) {
  const void* x     = d_in[0];   // [32][1024][1024]
  const void* lats  = d_in[1];   // [64][1024]
  const void* nm_g  = d_in[2];
  const void* nm_b  = d_in[3];
  const void* nl_g  = d_in[4];
  const void* nl_b  = d_in[5];
  const void* wq    = d_in[6];   // [6][1024][1024]
  const void* wkv   = d_in[7];   // [6][1024][2048]
  const void* wo    = d_in[8];   // [6][1024][1024]
  const void* ff_g  = d_in[9];
  const void* ff_b  = d_in[10];
  const void* w1    = d_in[11];  // [6][1024][4096]
  const void* w2    = d_in[12];  // [6][4096][1024]
  const void* fin_g = d_in[13];
  const void* fin_b = d_in[14];

  // --- workspace carve (runtime-adaptive; deterministic given ws_size) ---
  const size_t MB = 1024ull * 1024ull;
  char* w = (char*)d_ws;
  int*   flag = (int*)w;    w += 1 * MB;   // dtype flag
  float* lat  = (float*)w;  w += 8 * MB;   // residual stream fp32 [2048][1024]
  u16*   lnl  = (u16*)w;    w += 4 * MB;   // LN(lat); reused as LN pre-FF
  u16*   qbuf = (u16*)w;    w += 4 * MB;   // q [2048][1024]
  u16*   ao   = (u16*)w;    w += 4 * MB;   // attention out [2048][1024]
  u16*   kvl  = (u16*)w;    w += 8 * MB;   // latent k|v [2048][2048]
  u16*   h1   = (u16*)w;    w += 16 * MB;  // gelu(lat@w1) [2048][4096]
  u16*   wqt  = (u16*)w;    w += 2 * MB;   // wq^T  bf16 [1024][1024]
  u16*   wkvt = (u16*)w;    w += 4 * MB;   // wkv^T bf16 [2048][1024]
  u16*   wot  = (u16*)w;    w += 2 * MB;   // wo^T  bf16 [1024][1024]
  u16*   w1t  = (u16*)w;    w += 8 * MB;   // w1^T  bf16 [4096][1024]
  u16*   w2t  = (u16*)w;    w += 8 * MB;   // w2^T  bf16 [1024][4096]
  const size_t base = 69 * MB;
  int CH = 32;  // media chunk: CH groups at a time; 6 MiB per group
  while (CH > 1 && base + (size_t)CH * 6 * MB > ws_size) CH >>= 1;
  u16* xn  = (u16*)w;  w += (size_t)CH * 2 * MB;  // LN(x) chunk
  u16* kvm = (u16*)w;                             // media k|v [CH*1024][2048]
  const int nch = 32 / CH;

  detect_kernel<<<1, 64, 0, stream>>>((const u16*)x, flag);
  init_lat_kernel<<<2048, 256, 0, stream>>>(lats, lat, flag);

  for (int i = 0; i < 6; ++i) {
    // one-time per-layer weight convert+transpose to bf16 [N][K]
    wtrans_kernel<<<dim3(16, 16), 256, 0, stream>>>(
        wq, (long)i * 1024 * 1024, wqt, 1024, 1024, flag);
    wtrans_kernel<<<dim3(16, 32), 256, 0, stream>>>(
        wkv, (long)i * 1024 * 2048, wkvt, 1024, 2048, flag);
    wtrans_kernel<<<dim3(16, 16), 256, 0, stream>>>(
        wo, (long)i * 1024 * 1024, wot, 1024, 1024, flag);
    wtrans_kernel<<<dim3(16, 64), 256, 0, stream>>>(
        w1, (long)i * 1024 * 4096, w1t, 1024, 4096, flag);
    wtrans_kernel<<<dim3(64, 16), 256, 0, stream>>>(
        w2, (long)i * 4096 * 1024, w2t, 4096, 1024, flag);

    ln_kernel<1, 0><<<2048, 256, 0, stream>>>(
        lat, 0, nl_g, nl_b, (long)i * 1024, lnl, flag);
    gemm_kernel<0><<<dim3(16, 8), 256, 0, stream>>>(
        lnl, wqt, qbuf, nullptr, 2048, 1024, 1024);
    gemm_kernel<0><<<dim3(16, 16), 256, 0, stream>>>(
        lnl, wkvt, kvl, nullptr, 2048, 2048, 1024);
    for (int c = 0; c < nch; ++c) {
      ln_kernel<0, 0><<<CH * 1024, 256, 0, stream>>>(
          x, (long)c * CH * 1024 * 1024, nm_g, nm_b, (long)i * 1024, xn, flag);
      gemm_kernel<0><<<dim3(CH * 8, 16), 256, 0, stream>>>(
          xn, wkvt, kvm, nullptr, CH * 1024, 2048, 1024);
      attn_kernel<<<dim3(CH, 16), 256, 0, stream>>>(qbuf, kvm, kvl, ao, c * CH);
    }
    gemm_kernel<2><<<dim3(16, 8), 256, 0, stream>>>(
        ao, wot, lat, lat, 2048, 1024, 1024);
    ln_kernel<1, 0><<<2048, 256, 0, stream>>>(
        lat, 0, ff_g, ff_b, (long)i * 1024, lnl, flag);
    gemm_kernel<1><<<dim3(16, 32), 256, 0, stream>>>(
        lnl, w1t, h1, nullptr, 2048, 4096, 1024);
    gemm_kernel<2><<<dim3(16, 8), 256, 0, stream>>>(
        h1, w2t, lat, lat, 2048, 1024, 4096);
  }
  ln_kernel<1, 1><<<2048, 256, 0, stream>>>(
      lat, 0, fin_g, fin_b, 0, d_out, flag);
}